// Round 1
// baseline (606.975 us; speedup 1.0000x reference)
//
#include <hip/hip_runtime.h>
#include <hip/hip_bf16.h>
#include <stdint.h>

// Problem constants (fixed by reference setup_inputs)
#define T_ 800
#define B_ 16
#define D_ 256
#define V_ 4001
#define U_ 100
#define S_ 201      // 2U+1
#define SP 204      // S padded to multiple of 4 for float4 loads in alpha
#define M_ (T_*B_)  // 12800 GEMM rows
#define NEGF (-1e30f)
#define L2E 1.4426950408889634f
#define LN2 0.6931471805599453f

typedef __bf16 bf16;
typedef __bf16 bf16x8 __attribute__((ext_vector_type(8)));
typedef float f32x4 __attribute__((ext_vector_type(4)));

// Workspace layout (bytes). Total ~19.2 MB.
#define A_OFF     0          // bf16 A[12800][256]            6,553,600
#define WT_OFF    6553600    // bf16 Wt[4096][256] (padded)   2,097,152
#define EMIT_OFF  8650752    // f32 emit[B][T][SP] (log2 domain) 10,444,800
#define EXT_OFF   19095552   // i32 ext[16][204]                 13,056
#define AMASK_OFF 19108608   // f32 amask[16][204] (additive)    13,056
#define LENS_OFF  19121664   // i32 lens[16]

// ---------------- prep: ext labels, allow-mask (additive), label lens ----
__global__ void prep_kernel(const int* __restrict__ y, float* __restrict__ out,
                            int* __restrict__ ext, float* __restrict__ amask,
                            int* __restrict__ lens) {
  const int tid = threadIdx.x;
  if (tid == 0) out[0] = 0.f;  // loss accumulator (alpha atomicAdds later)
  if (tid < B_) {
    int cnt = 0;
    for (int u = 0; u < U_; u++) cnt += (y[u*B_ + tid] != 1) ? 1 : 0;
    lens[tid] = cnt;
  }
  for (int idx = tid; idx < B_*SP; idx += 256) {
    int b = idx / SP, s = idx - b*SP;
    int e = 0;
    if (s < S_ && (s & 1)) e = y[((s-1) >> 1)*B_ + b];
    ext[idx] = e;
    float am = NEGF;  // additive mask for the s-2 transition (log domain)
    if ((s & 1) && s >= 3 && s < S_) {
      int e2 = y[((s-3) >> 1)*B_ + b];
      if (e != 0 && e != e2) am = 0.f;
    }
    amask[idx] = am;
  }
}

// ---------------- cast ctx (f32) -> A (bf16), element-wise ---------------
__global__ void cast_a_kernel(const float* __restrict__ ctx, bf16* __restrict__ A) {
  int i = blockIdx.x * blockDim.x + threadIdx.x;  // exactly 819200 threads
  float4 v = ((const float4*)ctx)[i];
  union { bf16 h[4]; uint2 u; } p;
  p.h[0] = (bf16)v.x; p.h[1] = (bf16)v.y; p.h[2] = (bf16)v.z; p.h[3] = (bf16)v.w;
  ((uint2*)A)[i] = p.u;
}

// ---------------- transpose W [256][4001] f32 -> Wt [4096][256] bf16 -----
__global__ void trans_w_kernel(const float* __restrict__ W, bf16* __restrict__ Wt) {
  __shared__ float tile[32][33];
  const int c = threadIdx.x & 31, r = threadIdx.x >> 5;  // 32x8 threads
  const int n0 = blockIdx.x * 32, k0 = blockIdx.y * 32;
  for (int rr = r; rr < 32; rr += 8) {
    int n = n0 + c;
    tile[rr][c] = (n < V_) ? W[(size_t)(k0+rr)*V_ + n] : 0.f;
  }
  __syncthreads();
  for (int rr = r; rr < 32; rr += 8) {
    Wt[(size_t)(n0+rr)*D_ + k0 + c] = (bf16)tile[c][rr];
  }
}

// ---------------- GEMM: logits = A x Wt^T + bias -> out[1..] (f32) -------
// 128x128 tile, BK=64, mfma_f32_16x16x32_bf16, wave tile 64x64 (4x4 C-tiles)
// LDS row stride 72 bf16 (144 B = 9*16 B) -> bank-uniform b128 reads.
__global__ __launch_bounds__(256) void gemm_kernel(
    const bf16* __restrict__ A, const bf16* __restrict__ Wt,
    const float* __restrict__ bias, float* __restrict__ out) {
  __shared__ bf16 smA[128*72];
  __shared__ bf16 smB[128*72];
  const int tid = threadIdx.x;
  const int l = tid & 63, w = tid >> 6;
  const int wr = w >> 1, wc = w & 1;
  const int n0 = blockIdx.x * 128, m0 = blockIdx.y * 128;

  f32x4 acc[4][4];
#pragma unroll
  for (int i = 0; i < 4; i++)
#pragma unroll
    for (int j = 0; j < 4; j++) acc[i][j] = (f32x4){0.f, 0.f, 0.f, 0.f};

  for (int kt = 0; kt < 4; kt++) {
#pragma unroll
    for (int r = 0; r < 4; r++) {
      int j = (w*4 + r)*64 + l;        // 0..1023 16B-chunk slot
      int row = j >> 3, c = j & 7;     // row 0..127, chunk 0..7 (8 bf16)
      bf16x8 va = *(const bf16x8*)(A  + (size_t)(m0+row)*D_ + kt*64 + c*8);
      bf16x8 vb = *(const bf16x8*)(Wt + (size_t)(n0+row)*D_ + kt*64 + c*8);
      *(bf16x8*)((char*)smA + row*144 + (c<<4)) = va;
      *(bf16x8*)((char*)smB + row*144 + (c<<4)) = vb;
    }
    __syncthreads();
#pragma unroll
    for (int ks = 0; ks < 2; ks++) {
      bf16x8 af[4], bfr[4];
      const int cidx = ks*4 + (l >> 4);
#pragma unroll
      for (int t = 0; t < 4; t++) {
        int arow = wr*64 + t*16 + (l & 15);
        af[t]  = *(const bf16x8*)((const char*)smA + arow*144 + (cidx<<4));
        int brow = wc*64 + t*16 + (l & 15);
        bfr[t] = *(const bf16x8*)((const char*)smB + brow*144 + (cidx<<4));
      }
#pragma unroll
      for (int i = 0; i < 4; i++)
#pragma unroll
        for (int j = 0; j < 4; j++)
          acc[i][j] = __builtin_amdgcn_mfma_f32_16x16x32_bf16(af[i], bfr[j], acc[i][j], 0, 0, 0);
    }
    __syncthreads();
  }
  // epilogue: C layout col=lane&15, row=(lane>>4)*4+reg (verified m89/m91)
#pragma unroll
  for (int j = 0; j < 4; j++) {
    int gn = n0 + wc*64 + j*16 + (l & 15);
    if (gn < V_) {
      float bv = bias[gn];
#pragma unroll
      for (int i = 0; i < 4; i++) {
        int rbase = m0 + wr*64 + i*16 + ((l >> 4) << 2);
#pragma unroll
        for (int rg = 0; rg < 4; rg++) {
          out[1 + (size_t)(rbase + rg)*V_ + gn] = acc[i][j][rg] + bv;
        }
      }
    }
  }
}

// ---------------- per-row log_softmax in place + emit gather -------------
// emit stored TRANSPOSED [b][t][SP], log2 domain (pre-scaled by log2(e)).
__global__ __launch_bounds__(256) void softmax_gather_kernel(
    float* __restrict__ out, const int* __restrict__ ext, float* __restrict__ emit) {
  __shared__ float srow[4096];
  __shared__ float red[8];
  const int row = blockIdx.x, tid = threadIdx.x;
  float* rp = out + 1 + (size_t)row * V_;
  float v[16];
  float mx = NEGF;
#pragma unroll
  for (int j = 0; j < 16; j++) {
    int c = tid + j*256;
    v[j] = (c < V_) ? rp[c] : NEGF;
    mx = fmaxf(mx, v[j]);
  }
#pragma unroll
  for (int o = 32; o > 0; o >>= 1) mx = fmaxf(mx, __shfl_xor(mx, o));
  if ((tid & 63) == 0) red[tid >> 6] = mx;
  __syncthreads();
  mx = fmaxf(fmaxf(red[0], red[1]), fmaxf(red[2], red[3]));
  float sm = 0.f;
#pragma unroll
  for (int j = 0; j < 16; j++) sm += exp2f((v[j] - mx) * L2E);
#pragma unroll
  for (int o = 32; o > 0; o >>= 1) sm += __shfl_xor(sm, o);
  if ((tid & 63) == 0) red[4 + (tid >> 6)] = sm;
  __syncthreads();
  const float lse = mx + log2f(red[4] + red[5] + red[6] + red[7]) * LN2;
#pragma unroll
  for (int j = 0; j < 16; j++) {
    int c = tid + j*256;
    if (c < V_) {
      float lp = v[j] - lse;
      rp[c] = lp;        // final logps output
      srow[c] = lp;      // for the emit gather below
    }
  }
  __syncthreads();
  // emit in log2 domain: alpha runs in log2, avoids mul-by-L2E per step
  if (tid < SP) {
    float e = NEGF;
    if (tid < S_) e = srow[ext[(row & (B_-1))*SP + tid]] * L2E;
    emit[((size_t)(row & (B_-1))*T_ + (row >> 4))*SP + tid] = e;
  }
}

// ---------------- CTC alpha recursion (log2 domain) ----------------------
// R2 finding: the old single-wave 16-deep float4 register pipeline never
// materialized -- VGPR_Count=52 proves the compiler sank the prefetch loads
// to their use points, exposing ~600+ cycles of load latency per step
// (253 us total, VALUBusy 1.2%). Fix: producer/consumer waves. Block = 4
// waves; wave 0 runs the (unchanged) recursion reading emissions from a
// double-buffered LDS ring; waves 1-3 stage the next 32-timestep chunk
// into LDS. __syncthreads() per chunk: producers' load latency drains
// while the consumer computes the current chunk (~1800 cyc of lae/shfl
// chain vs ~1000 cyc HBM/L2 latency).
__device__ __forceinline__ float lae3_2(float a, float b, float c) {
  float m = fmaxf(fmaxf(a, b), c);
  float s = exp2f(a - m) + exp2f(b - m) + exp2f(c - m);
  return m + log2f(s);
}

#define CH 32  // timesteps per LDS chunk; 799 steps = 24 full chunks + 31 tail

__global__ __launch_bounds__(256) void alpha_kernel(
    const float* __restrict__ emit, const float* __restrict__ amp,
    const int* __restrict__ lens, float* __restrict__ out) {
  __shared__ float ring[2][CH][256];  // 64 KB: 2 buffers x 32 t x 1024 B
  __shared__ float aS[256];
  const int b = blockIdx.x;
  const int tid = threadIdx.x;
  const int wv = tid >> 6, l = tid & 63;
  const bool act = (l < 51);  // 51*4 = 204 = SP
  const float* ebase = emit + (size_t)b*T_*SP;
  const float4 NEG4 = make_float4(NEGF, NEGF, NEGF, NEGF);

  float a0 = NEGF, a1 = NEGF, a2 = NEGF, a3 = NEGF;
  float4 am = NEG4;

  if (wv == 0) {
    // consumer init: alpha0 has only s=0,1 reachable (emit already log2)
    if (act) am = *(const float4*)(amp + b*SP + 4*l);
    if (l == 0) { a0 = ebase[0]; a1 = ebase[1]; }
  } else if (act) {
    // producers: stage chunk 0 (t = 1..32) into ring[0]
    for (int j = wv - 1; j < CH; j += 3) {
      float4 v = *(const float4*)(ebase + (size_t)(1 + j)*SP + 4*l);
      *(float4*)&ring[0][j][4*l] = v;
    }
  }
  __syncthreads();  // chunk 0 ready

  auto step = [&](const float* slot) {
    float4 cur = act ? *(const float4*)(slot + 4*l) : NEG4;
    float sh1 = __shfl_up(a3, 1);  // alpha[s-1] for state 4l
    float sh2 = __shfl_up(a2, 1);  // alpha[s-2] for state 4l
    if (l == 0) { sh1 = NEGF; sh2 = NEGF; }
    float n0 = lae3_2(a0, sh1, sh2 + am.x) + cur.x;
    float n1 = lae3_2(a1, a0,  sh1 + am.y) + cur.y;
    float n2 = lae3_2(a2, a1,  a0  + am.z) + cur.z;
    float n3 = lae3_2(a3, a2,  a1  + am.w) + cur.w;
    a0 = n0; a1 = n1; a2 = n2; a3 = n3;
  };

  // main: 24 chunks of 32 steps -> t = 1..768; producers stay one chunk ahead
  for (int c = 0; c < 24; c++) {
    if (wv) {
      if (act) {
        const int base_t = 1 + (c + 1)*CH;
        float* dst = &ring[(c + 1) & 1][0][0];
        for (int j = wv - 1; j < CH; j += 3) {
          int t = base_t + j;
          if (t > T_ - 1) t = T_ - 1;  // tail clamp (slots unused by consumer)
          float4 v = *(const float4*)(ebase + (size_t)t*SP + 4*l);
          *(float4*)(dst + j*256 + 4*l) = v;
        }
      }
    } else {
      const float* src = &ring[c & 1][0][0];
#pragma unroll
      for (int j = 0; j < CH; j++) step(src + j*256);
    }
    __syncthreads();
  }
  // tail: chunk 24 in ring[0], t = 769..799 (31 steps)
  if (wv == 0) {
    const float* src = &ring[0][0][0];
#pragma unroll
    for (int j = 0; j < 31; j++) step(src + j*256);
    aS[4*l+0] = a0; aS[4*l+1] = a1; aS[4*l+2] = a2; aS[4*l+3] = a3;
  }
  __syncthreads();
  if (tid == 0) {
    int e = 2 * lens[b];
    float la = aS[e], lb = aS[e-1];
    float m = fmaxf(la, lb);
    float ll2 = m + log2f(exp2f(la - m) + exp2f(lb - m));
    atomicAdd(out, -ll2 * LN2);  // loss = -sum_b ll
  }
}

// ---------------- launch ----------------
extern "C" void kernel_launch(void* const* d_in, const int* in_sizes, int n_in,
                              void* d_out, int out_size, void* d_ws, size_t ws_size,
                              hipStream_t stream) {
  const float* ctx  = (const float*)d_in[0];  // [800,16,256]
  const int*   y    = (const int*)  d_in[1];  // [100,16]
  const float* W    = (const float*)d_in[2];  // [256,4001]
  const float* bias = (const float*)d_in[3];  // [4001]
  float* out = (float*)d_out;                 // [1 + 800*16*4001]
  char* ws = (char*)d_ws;
  bf16*  A     = (bf16*) (ws + A_OFF);
  bf16*  Wt    = (bf16*) (ws + WT_OFF);
  float* emit  = (float*)(ws + EMIT_OFF);
  int*   ext   = (int*)  (ws + EXT_OFF);
  float* amp   = (float*)(ws + AMASK_OFF);
  int*   lens  = (int*)  (ws + LENS_OFF);

  hipLaunchKernelGGL(prep_kernel, dim3(1), dim3(256), 0, stream, y, out, ext, amp, lens);
  hipLaunchKernelGGL(cast_a_kernel, dim3(3200), dim3(256), 0, stream, ctx, A);
  hipLaunchKernelGGL(trans_w_kernel, dim3(128, 8), dim3(256), 0, stream, W, Wt);
  hipLaunchKernelGGL(gemm_kernel, dim3(32, 100), dim3(256), 0, stream, A, Wt, bias, out);
  hipLaunchKernelGGL(softmax_gather_kernel, dim3(12800), dim3(256), 0, stream, out, ext, emit);
  hipLaunchKernelGGL(alpha_kernel, dim3(16), dim3(256), 0, stream, emit, amp, lens, out);
}

// Round 2
// 468.226 us; speedup vs baseline: 1.2963x; 1.2963x over previous
//
#include <hip/hip_runtime.h>
#include <hip/hip_bf16.h>
#include <stdint.h>

// Problem constants (fixed by reference setup_inputs)
#define T_ 800
#define B_ 16
#define D_ 256
#define V_ 4001
#define U_ 100
#define S_ 201      // 2U+1
#define SP 204      // S padded to multiple of 4 for float4 loads in alpha
#define M_ (T_*B_)  // 12800 GEMM rows
#define NEGF (-1e30f)
#define L2E 1.4426950408889634f
#define LN2 0.6931471805599453f

typedef __bf16 bf16;
typedef __bf16 bf16x8 __attribute__((ext_vector_type(8)));
typedef float f32x4 __attribute__((ext_vector_type(4)));

// Workspace layout (bytes). Total ~19.2 MB.
#define A_OFF     0          // bf16 A[12800][256]            6,553,600
#define WT_OFF    6553600    // bf16 Wt[4096][256] (padded)   2,097,152
#define EMIT_OFF  8650752    // f32 emit[B][T][SP] (log2 domain) 10,444,800
#define EXT_OFF   19095552   // i32 ext[16][204]                 13,056
#define AMASK_OFF 19108608   // f32 amask[16][204] (additive)    13,056
#define LENS_OFF  19121664   // i32 lens[16]

// ---------------- prep: ext labels, allow-mask (additive), label lens ----
__global__ void prep_kernel(const int* __restrict__ y, float* __restrict__ out,
                            int* __restrict__ ext, float* __restrict__ amask,
                            int* __restrict__ lens) {
  const int tid = threadIdx.x;
  if (tid == 0) out[0] = 0.f;  // loss accumulator (alpha atomicAdds later)
  if (tid < B_) {
    int cnt = 0;
    for (int u = 0; u < U_; u++) cnt += (y[u*B_ + tid] != 1) ? 1 : 0;
    lens[tid] = cnt;
  }
  for (int idx = tid; idx < B_*SP; idx += 256) {
    int b = idx / SP, s = idx - b*SP;
    int e = 0;
    if (s < S_ && (s & 1)) e = y[((s-1) >> 1)*B_ + b];
    ext[idx] = e;
    float am = NEGF;  // additive mask for the s-2 transition (log domain)
    if ((s & 1) && s >= 3 && s < S_) {
      int e2 = y[((s-3) >> 1)*B_ + b];
      if (e != 0 && e != e2) am = 0.f;
    }
    amask[idx] = am;
  }
}

// ---------------- cast ctx (f32) -> A (bf16), element-wise ---------------
__global__ void cast_a_kernel(const float* __restrict__ ctx, bf16* __restrict__ A) {
  int i = blockIdx.x * blockDim.x + threadIdx.x;  // exactly 819200 threads
  float4 v = ((const float4*)ctx)[i];
  union { bf16 h[4]; uint2 u; } p;
  p.h[0] = (bf16)v.x; p.h[1] = (bf16)v.y; p.h[2] = (bf16)v.z; p.h[3] = (bf16)v.w;
  ((uint2*)A)[i] = p.u;
}

// ---------------- transpose W [256][4001] f32 -> Wt [4096][256] bf16 -----
__global__ void trans_w_kernel(const float* __restrict__ W, bf16* __restrict__ Wt) {
  __shared__ float tile[32][33];
  const int c = threadIdx.x & 31, r = threadIdx.x >> 5;  // 32x8 threads
  const int n0 = blockIdx.x * 32, k0 = blockIdx.y * 32;
  for (int rr = r; rr < 32; rr += 8) {
    int n = n0 + c;
    tile[rr][c] = (n < V_) ? W[(size_t)(k0+rr)*V_ + n] : 0.f;
  }
  __syncthreads();
  for (int rr = r; rr < 32; rr += 8) {
    Wt[(size_t)(n0+rr)*D_ + k0 + c] = (bf16)tile[c][rr];
  }
}

// ---------------- GEMM: logits = A x Wt^T + bias -> out[1..] (f32) -------
// 128x128 tile, BK=64, mfma_f32_16x16x32_bf16, wave tile 64x64 (4x4 C-tiles)
// LDS row stride 72 bf16 (144 B = 9*16 B) -> bank-uniform b128 reads.
__global__ __launch_bounds__(256) void gemm_kernel(
    const bf16* __restrict__ A, const bf16* __restrict__ Wt,
    const float* __restrict__ bias, float* __restrict__ out) {
  __shared__ bf16 smA[128*72];
  __shared__ bf16 smB[128*72];
  const int tid = threadIdx.x;
  const int l = tid & 63, w = tid >> 6;
  const int wr = w >> 1, wc = w & 1;
  const int n0 = blockIdx.x * 128, m0 = blockIdx.y * 128;

  f32x4 acc[4][4];
#pragma unroll
  for (int i = 0; i < 4; i++)
#pragma unroll
    for (int j = 0; j < 4; j++) acc[i][j] = (f32x4){0.f, 0.f, 0.f, 0.f};

  for (int kt = 0; kt < 4; kt++) {
#pragma unroll
    for (int r = 0; r < 4; r++) {
      int j = (w*4 + r)*64 + l;        // 0..1023 16B-chunk slot
      int row = j >> 3, c = j & 7;     // row 0..127, chunk 0..7 (8 bf16)
      bf16x8 va = *(const bf16x8*)(A  + (size_t)(m0+row)*D_ + kt*64 + c*8);
      bf16x8 vb = *(const bf16x8*)(Wt + (size_t)(n0+row)*D_ + kt*64 + c*8);
      *(bf16x8*)((char*)smA + row*144 + (c<<4)) = va;
      *(bf16x8*)((char*)smB + row*144 + (c<<4)) = vb;
    }
    __syncthreads();
#pragma unroll
    for (int ks = 0; ks < 2; ks++) {
      bf16x8 af[4], bfr[4];
      const int cidx = ks*4 + (l >> 4);
#pragma unroll
      for (int t = 0; t < 4; t++) {
        int arow = wr*64 + t*16 + (l & 15);
        af[t]  = *(const bf16x8*)((const char*)smA + arow*144 + (cidx<<4));
        int brow = wc*64 + t*16 + (l & 15);
        bfr[t] = *(const bf16x8*)((const char*)smB + brow*144 + (cidx<<4));
      }
#pragma unroll
      for (int i = 0; i < 4; i++)
#pragma unroll
        for (int j = 0; j < 4; j++)
          acc[i][j] = __builtin_amdgcn_mfma_f32_16x16x32_bf16(af[i], bfr[j], acc[i][j], 0, 0, 0);
    }
    __syncthreads();
  }
  // epilogue: C layout col=lane&15, row=(lane>>4)*4+reg (verified m89/m91)
#pragma unroll
  for (int j = 0; j < 4; j++) {
    int gn = n0 + wc*64 + j*16 + (l & 15);
    if (gn < V_) {
      float bv = bias[gn];
#pragma unroll
      for (int i = 0; i < 4; i++) {
        int rbase = m0 + wr*64 + i*16 + ((l >> 4) << 2);
#pragma unroll
        for (int rg = 0; rg < 4; rg++) {
          out[1 + (size_t)(rbase + rg)*V_ + gn] = acc[i][j][rg] + bv;
        }
      }
    }
  }
}

// ---------------- per-row log_softmax in place + emit gather -------------
// emit stored TRANSPOSED [b][t][SP], log2 domain (pre-scaled by log2(e)).
__global__ __launch_bounds__(256) void softmax_gather_kernel(
    float* __restrict__ out, const int* __restrict__ ext, float* __restrict__ emit) {
  __shared__ float srow[4096];
  __shared__ float red[8];
  const int row = blockIdx.x, tid = threadIdx.x;
  float* rp = out + 1 + (size_t)row * V_;
  float v[16];
  float mx = NEGF;
#pragma unroll
  for (int j = 0; j < 16; j++) {
    int c = tid + j*256;
    v[j] = (c < V_) ? rp[c] : NEGF;
    mx = fmaxf(mx, v[j]);
  }
#pragma unroll
  for (int o = 32; o > 0; o >>= 1) mx = fmaxf(mx, __shfl_xor(mx, o));
  if ((tid & 63) == 0) red[tid >> 6] = mx;
  __syncthreads();
  mx = fmaxf(fmaxf(red[0], red[1]), fmaxf(red[2], red[3]));
  float sm = 0.f;
#pragma unroll
  for (int j = 0; j < 16; j++) sm += exp2f((v[j] - mx) * L2E);
#pragma unroll
  for (int o = 32; o > 0; o >>= 1) sm += __shfl_xor(sm, o);
  if ((tid & 63) == 0) red[4 + (tid >> 6)] = sm;
  __syncthreads();
  const float lse = mx + log2f(red[4] + red[5] + red[6] + red[7]) * LN2;
#pragma unroll
  for (int j = 0; j < 16; j++) {
    int c = tid + j*256;
    if (c < V_) {
      float lp = v[j] - lse;
      rp[c] = lp;        // final logps output
      srow[c] = lp;      // for the emit gather below
    }
  }
  __syncthreads();
  // emit in log2 domain: alpha runs in log2, avoids mul-by-L2E per step
  if (tid < SP) {
    float e = NEGF;
    if (tid < S_) e = srow[ext[(row & (B_-1))*SP + tid]] * L2E;
    emit[((size_t)(row & (B_-1))*T_ + (row >> 4))*SP + tid] = e;
  }
}

// ---------------- CTC alpha recursion (log2 domain) ----------------------
// R2 post-mortem: R1's producer/consumer LDS staging was neutral (253->270us)
// -> global latency was NOT the bottleneck. The ~760 cyc/step is the serial
// dependent chain itself: (a) __shfl_up = ds_bpermute + lgkmcnt(0) wait,
// ~120+ cyc each; (b) exp2f/log2f OCML libcalls with range-fixup code
// (VALUBusy -> ~72 VALU inst/step issued). R2 fix, keeping the LDS staging:
//   1. DPP wave_shr:1 (v_mov_dpp, ~8 cyc) replaces both shfls; old=NEGF
//      gives the lane-0 boundary for free.
//   2. Raw v_exp_f32/v_log_f32 via __builtin_amdgcn_exp2f/logf (~1 ULP,
//      inputs bounded, no denormal concerns in log2 domain).
//   3. lae3 via max3/med3/min3: exp2(max-max)==1 statically, so
//      s = 1 + exp2(med-m) + exp2(min-m) -- 8 exp2/step instead of 12.
__device__ __forceinline__ float dpp_shr1(float x) {
  // lane l gets lane l-1's x; lane 0 gets 'old' = NEGF (bound_ctrl=0 keeps old)
  int r = __builtin_amdgcn_update_dpp(__float_as_int(NEGF), __float_as_int(x),
                                      0x138 /*wave_shr:1*/, 0xf, 0xf, false);
  return __int_as_float(r);
}

__device__ __forceinline__ float lae3(float a, float b, float c) {
  float m  = fmaxf(fmaxf(a, b), c);                 // v_max3_f32
  float md = __builtin_amdgcn_fmed3f(a, b, c);      // v_med3_f32
  float mn = fminf(fminf(a, b), c);                 // v_min3_f32
  float s = 1.0f + __builtin_amdgcn_exp2f(md - m) + __builtin_amdgcn_exp2f(mn - m);
  return m + __builtin_amdgcn_logf(s);              // v_log_f32 (log2)
}

#define CH 32  // timesteps per LDS chunk; 799 steps = 24 full chunks + 31 tail

__global__ __launch_bounds__(256) void alpha_kernel(
    const float* __restrict__ emit, const float* __restrict__ amp,
    const int* __restrict__ lens, float* __restrict__ out) {
  __shared__ float ring[2][CH][256];  // 64 KB: 2 buffers x 32 t x 1024 B
  __shared__ float aS[256];
  const int b = blockIdx.x;
  const int tid = threadIdx.x;
  const int wv = tid >> 6, l = tid & 63;
  const bool act = (l < 51);  // 51*4 = 204 = SP
  const float* ebase = emit + (size_t)b*T_*SP;
  const float4 NEG4 = make_float4(NEGF, NEGF, NEGF, NEGF);

  float a0 = NEGF, a1 = NEGF, a2 = NEGF, a3 = NEGF;
  float4 am = NEG4;

  if (wv == 0) {
    // consumer init: alpha0 has only s=0,1 reachable (emit already log2)
    if (act) am = *(const float4*)(amp + b*SP + 4*l);
    if (l == 0) { a0 = ebase[0]; a1 = ebase[1]; }
  } else if (act) {
    // producers: stage chunk 0 (t = 1..32) into ring[0]
    for (int j = wv - 1; j < CH; j += 3) {
      float4 v = *(const float4*)(ebase + (size_t)(1 + j)*SP + 4*l);
      *(float4*)&ring[0][j][4*l] = v;
    }
  }
  __syncthreads();  // chunk 0 ready

  auto step = [&](const float* slot) {
    float4 cur = act ? *(const float4*)(slot + 4*l) : NEG4;
    float sh1 = dpp_shr1(a3);  // alpha[s-1] for state 4l
    float sh2 = dpp_shr1(a2);  // alpha[s-2] for state 4l
    float n0 = lae3(a0, sh1, sh2 + am.x) + cur.x;
    float n1 = lae3(a1, a0,  sh1 + am.y) + cur.y;
    float n2 = lae3(a2, a1,  a0  + am.z) + cur.z;
    float n3 = lae3(a3, a2,  a1  + am.w) + cur.w;
    a0 = n0; a1 = n1; a2 = n2; a3 = n3;
  };

  // main: 24 chunks of 32 steps -> t = 1..768; producers stay one chunk ahead
  for (int c = 0; c < 24; c++) {
    if (wv) {
      if (act) {
        const int base_t = 1 + (c + 1)*CH;
        float* dst = &ring[(c + 1) & 1][0][0];
        for (int j = wv - 1; j < CH; j += 3) {
          int t = base_t + j;
          if (t > T_ - 1) t = T_ - 1;  // tail clamp (slots unused by consumer)
          float4 v = *(const float4*)(ebase + (size_t)t*SP + 4*l);
          *(float4*)(dst + j*256 + 4*l) = v;
        }
      }
    } else {
      const float* src = &ring[c & 1][0][0];
#pragma unroll
      for (int j = 0; j < CH; j++) step(src + j*256);
    }
    __syncthreads();
  }
  // tail: chunk 24 in ring[0], t = 769..799 (31 steps)
  if (wv == 0) {
    const float* src = &ring[0][0][0];
#pragma unroll
    for (int j = 0; j < 31; j++) step(src + j*256);
    aS[4*l+0] = a0; aS[4*l+1] = a1; aS[4*l+2] = a2; aS[4*l+3] = a3;
  }
  __syncthreads();
  if (tid == 0) {
    int e = 2 * lens[b];
    float la = aS[e], lb = aS[e-1];
    float m = fmaxf(la, lb);
    float ll2 = m + log2f(exp2f(la - m) + exp2f(lb - m));
    atomicAdd(out, -ll2 * LN2);  // loss = -sum_b ll
  }
}

// ---------------- launch ----------------
extern "C" void kernel_launch(void* const* d_in, const int* in_sizes, int n_in,
                              void* d_out, int out_size, void* d_ws, size_t ws_size,
                              hipStream_t stream) {
  const float* ctx  = (const float*)d_in[0];  // [800,16,256]
  const int*   y    = (const int*)  d_in[1];  // [100,16]
  const float* W    = (const float*)d_in[2];  // [256,4001]
  const float* bias = (const float*)d_in[3];  // [4001]
  float* out = (float*)d_out;                 // [1 + 800*16*4001]
  char* ws = (char*)d_ws;
  bf16*  A     = (bf16*) (ws + A_OFF);
  bf16*  Wt    = (bf16*) (ws + WT_OFF);
  float* emit  = (float*)(ws + EMIT_OFF);
  int*   ext   = (int*)  (ws + EXT_OFF);
  float* amp   = (float*)(ws + AMASK_OFF);
  int*   lens  = (int*)  (ws + LENS_OFF);

  hipLaunchKernelGGL(prep_kernel, dim3(1), dim3(256), 0, stream, y, out, ext, amp, lens);
  hipLaunchKernelGGL(cast_a_kernel, dim3(3200), dim3(256), 0, stream, ctx, A);
  hipLaunchKernelGGL(trans_w_kernel, dim3(128, 8), dim3(256), 0, stream, W, Wt);
  hipLaunchKernelGGL(gemm_kernel, dim3(32, 100), dim3(256), 0, stream, A, Wt, bias, out);
  hipLaunchKernelGGL(softmax_gather_kernel, dim3(12800), dim3(256), 0, stream, out, ext, emit);
  hipLaunchKernelGGL(alpha_kernel, dim3(16), dim3(256), 0, stream, emit, amp, lens, out);
}